// Round 6
// baseline (7707.951 us; speedup 1.0000x reference)
//
#include <hip/hip_runtime.h>

typedef __bf16 bf16_t;
typedef __bf16 bf16x4 __attribute__((ext_vector_type(4)));
typedef __bf16 bf16x8 __attribute__((ext_vector_type(8)));
typedef float f32x16 __attribute__((ext_vector_type(16)));

#define DD 300
#define LDP 320
#define WSLOT (LDP * LDP)

struct Src12 { const float* p[12]; };

// wt[m][n*LDP + k] = W_m[k*DD + n], zero-padded to 320x320 (n-major, k-contig)
__global__ void prep_wt_all(Src12 s, bf16_t* __restrict__ wt) {
  int m = blockIdx.y;
  int idx = blockIdx.x * 256 + threadIdx.x;
  if (idx >= WSLOT) return;
  int n = idx / LDP, k = idx - n * LDP;
  float v = 0.f;
  if (n < DD && k < DD) v = s.p[m][(long)k * DD + n];
  wt[(size_t)m * WSLOT + idx] = (bf16_t)v;
}

__global__ void prep_wt_head(const float* __restrict__ ah_w, const float* __restrict__ ch_w,
                             bf16_t* __restrict__ wt) {
  int idx = blockIdx.x * 256 + threadIdx.x;
  if (idx >= WSLOT) return;
  int n = idx / LDP, k = idx - n * LDP;
  float v = 0.f;
  if (k < DD) {
    if (n < 87) v = ah_w[(long)k * 87 + n];
    else if (n < 93) v = ch_w[(long)k * 6 + (n - 87)];
  }
  wt[idx] = (bf16_t)v;
}

enum { MODE_F32 = 0, MODE_BF16_RELU = 1, MODE_BF16 = 2, MODE_EMB = 3, MODE_HEAD = 4 };

// C[M,320] = A[M,320(K)] @ W[320,320] + bias; tile 128 rows x 320 cols/block.
// 4 waves: wave owns rows (wave&1)*64 + {0,32}, cols (wave>>1)*160 + 32*{0..4}.
// LDS row stride 40 elems (80B): conflict-free ds_read_b128.
// In-place safe (outv==Av): each block reads A only from its own 128-row tile
// and stores strictly after its last A read.
template<bool ABF16, int MODE>
__global__ __launch_bounds__(256, 2)
void gemm_k(const void* __restrict__ Av, const bf16_t* __restrict__ Wt,
            const float* __restrict__ bias, void* __restrict__ outv, int M,
            const int* __restrict__ z, const float* __restrict__ emb,
            float* __restrict__ out2, const float* __restrict__ bias2)
{
  __shared__ bf16_t As[128 * 40];
  __shared__ bf16_t Bs[320 * 40];
  const int tid = threadIdx.x;
  const int wave = tid >> 6;
  const int lane = tid & 63;
  const int lhalf = lane >> 5;
  const int l31 = lane & 31;
  const int m0 = blockIdx.x * 128;

  f32x16 acc[2][5] = {};

  for (int k0 = 0; k0 < LDP; k0 += 32) {
    #pragma unroll
    for (int i = 0; i < 5; i++) {
      int idx = tid + i * 256;
      int n = idx >> 2, cv = idx & 3;
      *(bf16x8*)&Bs[n * 40 + cv * 8] =
          *(const bf16x8*)(Wt + (size_t)n * LDP + k0 + cv * 8);
    }
    if constexpr (ABF16) {
      const bf16_t* __restrict__ A = (const bf16_t*)Av;
      #pragma unroll
      for (int i = 0; i < 2; i++) {
        int r = (tid >> 2) + i * 64;
        int cv = tid & 3;
        int row = m0 + r;
        bf16x8 v = {};
        if (row < M) v = *(const bf16x8*)(A + (size_t)row * LDP + k0 + cv * 8);
        *(bf16x8*)&As[r * 40 + cv * 8] = v;
      }
    } else {
      const float* __restrict__ A = (const float*)Av;
      #pragma unroll
      for (int i = 0; i < 4; i++) {
        int r = (tid >> 3) + i * 32;
        int cv = tid & 7;
        int row = m0 + r;
        float fx = 0.f, fy = 0.f, fz2 = 0.f, fw = 0.f;
        if (row < M) {
          const float4 f = *(const float4*)(A + (size_t)row * LDP + k0 + cv * 4);
          fx = f.x; fy = f.y; fz2 = f.z; fw = f.w;
        }
        bf16x4 v;
        v.x = (bf16_t)fx; v.y = (bf16_t)fy; v.z = (bf16_t)fz2; v.w = (bf16_t)fw;
        *(bf16x4*)&As[r * 40 + cv * 4] = v;
      }
    }
    __syncthreads();
    #pragma unroll
    for (int ks = 0; ks < 2; ks++) {
      const int kk = ks * 16 + lhalf * 8;
      bf16x8 af0 = *(const bf16x8*)&As[((wave & 1) * 64 + 0  + l31) * 40 + kk];
      bf16x8 af1 = *(const bf16x8*)&As[((wave & 1) * 64 + 32 + l31) * 40 + kk];
      #pragma unroll
      for (int cf = 0; cf < 5; cf++) {
        bf16x8 bv = *(const bf16x8*)&Bs[((wave >> 1) * 160 + cf * 32 + l31) * 40 + kk];
        acc[0][cf] = __builtin_amdgcn_mfma_f32_32x32x16_bf16(af0, bv, acc[0][cf], 0, 0, 0);
        acc[1][cf] = __builtin_amdgcn_mfma_f32_32x32x16_bf16(af1, bv, acc[1][cf], 0, 0, 0);
      }
    }
    __syncthreads();
  }

  const int colb = (wave >> 1) * 160;
  #pragma unroll
  for (int rf = 0; rf < 2; rf++) {
    const int rowb = m0 + (wave & 1) * 64 + rf * 32 + 4 * lhalf;
    #pragma unroll
    for (int cf = 0; cf < 5; cf++) {
      const int col = colb + cf * 32 + l31;
      float bv;
      if constexpr (MODE == MODE_HEAD) {
        bv = (col < 87) ? bias[col] : (col < 93 ? bias2[col - 87] : 0.f);
      } else {
        bv = (col < DD) ? bias[col] : 0.f;
      }
      f32x16 v = acc[rf][cf];
      #pragma unroll
      for (int r = 0; r < 16; r++) {
        const int row = rowb + (r & 3) + 8 * (r >> 2);
        if (row >= M) continue;
        float val = v[r] + bv;
        if constexpr (MODE == MODE_F32) {
          ((float*)outv)[(size_t)row * LDP + col] = val;
        } else if constexpr (MODE == MODE_BF16_RELU) {
          ((bf16_t*)outv)[(size_t)row * LDP + col] = (bf16_t)fmaxf(val, 0.f);
        } else if constexpr (MODE == MODE_BF16) {
          ((bf16_t*)outv)[(size_t)row * LDP + col] = (bf16_t)val;
        } else if constexpr (MODE == MODE_EMB) {
          float add = (col < DD) ? emb[(size_t)z[row] * DD + col] : 0.f;
          ((bf16_t*)outv)[(size_t)row * LDP + col] = (bf16_t)(val + add);
        } else {  // MODE_HEAD: fp32 outputs (reference output dtype)
          if (col < 87) ((float*)outv)[(size_t)row * 87 + col] = val;
          else if (col < 93) out2[(size_t)row * 6 + (col - 87)] = val;
        }
      }
    }
  }
}

__global__ void stage1_node(const float* __restrict__ ch, const float* __restrict__ fc,
                            const float* __restrict__ w1, const float* __restrict__ b1,
                            bf16_t* __restrict__ t, int n) {
  int idx = blockIdx.x * 256 + threadIdx.x;
  if (idx >= n * LDP) return;
  int i = idx / LDP;
  int c = idx - i * LDP;
  float v = 0.f;
  if (c < DD) v = fmaxf(ch[i] * w1[c] + fc[i] * w1[DD + c] + b1[c], 0.f);
  t[idx] = (bf16_t)v;
}

__global__ void stage1_edge(const float* __restrict__ ea,
                            const float* __restrict__ w1, const float* __restrict__ b1,
                            bf16_t* __restrict__ t, int n) {
  int idx = blockIdx.x * 256 + threadIdx.x;
  if (idx >= n * LDP) return;
  int i = idx / LDP;
  int c = idx - i * LDP;
  float v = 0.f;
  if (c < DD) {
    float a0 = ea[(long)i * 3 + 0], a1 = ea[(long)i * 3 + 1], a2 = ea[(long)i * 3 + 2];
    v = fmaxf(a0 * w1[c] + a1 * w1[DD + c] + a2 * w1[2 * DD + c] + b1[c], 0.f);
  }
  t[idx] = (bf16_t)v;
}

// hh = (float)h (GINE eps=0 self term); atomics accumulate on top
__global__ void init_hh(const bf16_t* __restrict__ h, float* __restrict__ hh, int total) {
  int idx = blockIdx.x * 256 + threadIdx.x;
  if (idx >= total) return;
  hh[idx] = (float)h[idx];
}

// hh += scatter_add over dst of relu(h[src] + e)
__global__ void scatter_k(const bf16_t* __restrict__ h, const bf16_t* __restrict__ e,
                          const int* __restrict__ src, const int* __restrict__ dst,
                          float* __restrict__ hh, int E) {
  int idx = blockIdx.x * 256 + threadIdx.x;
  if (idx >= E * 75) return;
  int ed = idx / 75;
  int q = idx - ed * 75;
  int s = src[ed], d = dst[ed];
  const bf16x4 hv = *(const bf16x4*)(h + (size_t)s * LDP + q * 4);
  const bf16x4 ev = *(const bf16x4*)(e + (size_t)ed * LDP + q * 4);
  float* o = hh + (size_t)d * LDP + q * 4;
  atomicAdd(o + 0, fmaxf((float)hv.x + (float)ev.x, 0.f));
  atomicAdd(o + 1, fmaxf((float)hv.y + (float)ev.y, 0.f));
  atomicAdd(o + 2, fmaxf((float)hv.z + (float)ev.z, 0.f));
  atomicAdd(o + 3, fmaxf((float)hv.w + (float)ev.w, 0.f));
}

__global__ void zero_sums(float* __restrict__ sums) { sums[threadIdx.x] = 0.f; }

__global__ void bn_stats(const float* __restrict__ u, float* __restrict__ sums, int n) {
  int c = threadIdx.x;  // 0..319
  float s = 0.f, s2 = 0.f;
  for (int r = blockIdx.x; r < n; r += gridDim.x) {
    float v = u[(size_t)r * LDP + c];
    s += v; s2 += v * v;
  }
  if (c < DD) {
    atomicAdd(&sums[c], s);
    atomicAdd(&sums[LDP + c], s2);
  }
}

__global__ void bn_final(const float* __restrict__ sums, const float* __restrict__ gamma,
                         const float* __restrict__ beta, float* __restrict__ ab, int n) {
  int c = threadIdx.x;
  if (c >= DD) return;
  float inv_n = 1.f / (float)n;
  float mean = sums[c] * inv_n;
  float var = sums[LDP + c] * inv_n - mean * mean;  // biased var (torch/jnp)
  float a = gamma[c] * rsqrtf(fmaxf(var, 0.f) + 1e-5f);
  ab[c] = a;
  ab[LDP + c] = beta[c] - mean * a;
}

__global__ void bn_norm(const float* __restrict__ u, const float* __restrict__ ab,
                        bf16_t* __restrict__ h, int total) {
  int idx = blockIdx.x * 256 + threadIdx.x;
  if (idx >= total) return;
  int c = idx % LDP;
  float v = 0.f;
  if (c < DD) v = fmaxf(u[idx] * ab[c] + ab[LDP + c], 0.f);
  h[idx] = (bf16_t)v;  // pad columns stay zero
}

extern "C" void kernel_launch(void* const* d_in, const int* in_sizes, int n_in,
                              void* d_out, int out_size, void* d_ws, size_t ws_size,
                              hipStream_t stream) {
  const int*   z        = (const int*)d_in[0];
  const float* chir     = (const float*)d_in[1];
  const float* fchg     = (const float*)d_in[2];
  const int*   eidx     = (const int*)d_in[3];
  const float* eattr    = (const float*)d_in[4];
  const float* atom_emb = (const float*)d_in[5];
  const float* nap_w1   = (const float*)d_in[6];
  const float* nap_b1   = (const float*)d_in[7];
  const float* nap_w2   = (const float*)d_in[8];
  const float* nap_b2   = (const float*)d_in[9];
  const float* ee_w1    = (const float*)d_in[10];
  const float* ee_b1    = (const float*)d_in[11];
  const float* ee_w2    = (const float*)d_in[12];
  const float* ee_b2    = (const float*)d_in[13];
  const float* gnn_w1   = (const float*)d_in[14];
  const float* gnn_b1   = (const float*)d_in[15];
  const float* gnn_w2   = (const float*)d_in[16];
  const float* gnn_b2   = (const float*)d_in[17];
  const float* bn_gamma = (const float*)d_in[18];
  const float* bn_beta  = (const float*)d_in[19];
  const float* ah_w     = (const float*)d_in[20];
  const float* ah_b     = (const float*)d_in[21];
  const float* ch_w     = (const float*)d_in[22];
  const float* ch_b     = (const float*)d_in[23];

  const int N = in_sizes[0];
  const int E = in_sizes[3] / 2;
  const int* src = eidx;
  const int* dst = eidx + E;

  char* ws = (char*)d_ws;
  size_t off = 0;
  auto take = [&](size_t bytes) -> void* {
    void* p = ws + off;
    off = (off + bytes + 255) & ~(size_t)255;
    return p;
  };
  bf16_t* wt12 = (bf16_t*)take((size_t)12 * WSLOT * 2);
  bf16_t* wtH  = (bf16_t*)take((size_t)WSLOT * 2);
  float*  sums = (float*)take((size_t)2 * LDP * 4);
  float*  ab   = (float*)take((size_t)2 * LDP * 4);
  bf16_t* h    = (bf16_t*)take((size_t)N * LDP * 2);   // bf16 activations (+MLP temp)
  float*  hh   = (float*)take((size_t)N * LDP * 4);    // fp32 aggregate / pre-BN
  const size_t base_end = off;
  if (ws_size < base_end) return;  // can't run safely -> zero output (diagnostic)

  const size_t e_bytes = (size_t)E * LDP * 2;
  const bool persist_e = (ws_size >= base_end + e_bytes + 256) &&
                         (e_bytes <= (size_t)N * LDP * 4);  // estage aliases hh
  bf16_t* e_full = nullptr;
  bf16_t* echunk = nullptr;
  int EC = 0;
  if (persist_e) {
    e_full = (bf16_t*)take(e_bytes);
  } else {
    // chunked recompute per layer; estage borrows d_out (fp32, out_size*4 B)
    size_t slack = (ws_size > base_end + 256) ? (ws_size - base_end - 256) : 0;
    size_t ec_ws  = slack / (LDP * 2);
    size_t ec_out = ((size_t)out_size * 4) / (LDP * 2);
    size_t ec = ec_ws < ec_out ? ec_ws : ec_out;
    if (ec > (size_t)E) ec = E;
    ec &= ~(size_t)127;
    if (ec < 128) return;
    EC = (int)ec;
    echunk = (bf16_t*)take((size_t)EC * LDP * 2);
  }
  (void)n_in;

  Src12 s;
  s.p[0] = nap_w2; s.p[1] = ee_w2;
  for (int l = 0; l < 5; l++) {
    s.p[2 + l] = gnn_w1 + (size_t)l * DD * DD;
    s.p[7 + l] = gnn_w2 + (size_t)l * DD * DD;
  }
  prep_wt_all<<<dim3((WSLOT + 255) / 256, 12), 256, 0, stream>>>(s, wt12);
  prep_wt_head<<<(WSLOT + 255) / 256, 256, 0, stream>>>(ah_w, ch_w, wtH);

  const int gN = (N + 127) / 128;

  if (persist_e) {
    bf16_t* estage = (bf16_t*)hh;  // hh dead until first init_hh
    stage1_edge<<<((long)E * LDP + 255) / 256, 256, 0, stream>>>(eattr, ee_w1, ee_b1, estage, E);
    gemm_k<true, MODE_BF16><<<(E + 127) / 128, 256, 0, stream>>>(
        estage, wt12 + (size_t)1 * WSLOT, ee_b2, e_full, E, nullptr, nullptr, nullptr, nullptr);
  }

  // node init: h = atom_emb[z] + relu(na@nap_w1+b1)@nap_w2+b2  (bf16, in-place)
  stage1_node<<<((long)N * LDP + 255) / 256, 256, 0, stream>>>(chir, fchg, nap_w1, nap_b1, h, N);
  gemm_k<true, MODE_EMB><<<gN, 256, 0, stream>>>(
      h, wt12 + (size_t)0 * WSLOT, nap_b2, h, N, z, atom_emb, nullptr, nullptr);

  for (int l = 0; l < 5; l++) {
    init_hh<<<((long)N * LDP + 255) / 256, 256, 0, stream>>>(h, hh, N * LDP);
    if (persist_e) {
      scatter_k<<<((long)E * 75 + 255) / 256, 256, 0, stream>>>(h, e_full, src, dst, hh, E);
    } else {
      bf16_t* estage = (bf16_t*)d_out;  // legal scratch until final head GEMM
      for (int c0 = 0; c0 < E; c0 += EC) {
        int cur = (E - c0 < EC) ? (E - c0) : EC;
        stage1_edge<<<((long)cur * LDP + 255) / 256, 256, 0, stream>>>(
            eattr + (size_t)c0 * 3, ee_w1, ee_b1, estage, cur);
        gemm_k<true, MODE_BF16><<<(cur + 127) / 128, 256, 0, stream>>>(
            estage, wt12 + (size_t)1 * WSLOT, ee_b2, echunk, cur,
            nullptr, nullptr, nullptr, nullptr);
        scatter_k<<<((long)cur * 75 + 255) / 256, 256, 0, stream>>>(
            h, echunk, src + c0, dst + c0, hh, cur);
      }
    }
    gemm_k<false, MODE_BF16_RELU><<<gN, 256, 0, stream>>>(
        hh, wt12 + (size_t)(2 + l) * WSLOT, gnn_b1 + (size_t)l * DD, h, N,
        nullptr, nullptr, nullptr, nullptr);
    gemm_k<true, MODE_F32><<<gN, 256, 0, stream>>>(
        h, wt12 + (size_t)(7 + l) * WSLOT, gnn_b2 + (size_t)l * DD, hh, N,
        nullptr, nullptr, nullptr, nullptr);
    zero_sums<<<1, 2 * LDP, 0, stream>>>(sums);
    bn_stats<<<1024, LDP, 0, stream>>>(hh, sums, N);
    bn_final<<<1, LDP, 0, stream>>>(sums, bn_gamma + (size_t)l * DD, bn_beta + (size_t)l * DD, ab, N);
    bn_norm<<<((long)N * LDP + 255) / 256, 256, 0, stream>>>(hh, ab, h, N * LDP);
  }

  // heads: logits [N,87] ++ dists [N,6] into fp32 d_out
  gemm_k<true, MODE_HEAD><<<gN, 256, 0, stream>>>(
      h, wtH, ah_b, d_out, N, nullptr, nullptr, (float*)d_out + (size_t)N * 87, ch_b);
}

// Round 8
// 7331.447 us; speedup vs baseline: 1.0514x; 1.0514x over previous
//
#include <hip/hip_runtime.h>

typedef __bf16 bf16_t;
typedef __bf16 bf16x4 __attribute__((ext_vector_type(4)));
typedef __bf16 bf16x8 __attribute__((ext_vector_type(8)));
typedef float f32x16 __attribute__((ext_vector_type(16)));

#define DD 300
#define LDP 320
#define WSLOT (LDP * LDP)

struct Src12 { const float* p[12]; };

// wt[m][n*LDP + k] = W_m[k*DD + n], zero-padded to 320x320 (n-major, k-contig)
__global__ void prep_wt_all(Src12 s, bf16_t* __restrict__ wt) {
  int m = blockIdx.y;
  int idx = blockIdx.x * 256 + threadIdx.x;
  if (idx >= WSLOT) return;
  int n = idx / LDP, k = idx - n * LDP;
  float v = 0.f;
  if (n < DD && k < DD) v = s.p[m][(long)k * DD + n];
  wt[(size_t)m * WSLOT + idx] = (bf16_t)v;
}

__global__ void prep_wt_head(const float* __restrict__ ah_w, const float* __restrict__ ch_w,
                             bf16_t* __restrict__ wt) {
  int idx = blockIdx.x * 256 + threadIdx.x;
  if (idx >= WSLOT) return;
  int n = idx / LDP, k = idx - n * LDP;
  float v = 0.f;
  if (k < DD) {
    if (n < 87) v = ah_w[(long)k * 87 + n];
    else if (n < 93) v = ch_w[(long)k * 6 + (n - 87)];
  }
  wt[idx] = (bf16_t)v;
}

enum { MODE_F32S = 0, MODE_BF16_RELU = 1, MODE_BF16 = 2, MODE_EMB = 3, MODE_HEAD = 4 };

// C[M,320] = A[M,320(K)] @ W[320,320] + bias; 128 rows x 320 cols per block.
// MODE_F32S additionally accumulates per-column sum/sumsq into `out2`(=sums)
// via one atomicAdd per column per block (BN training stats fusion).
// NOTE: Av/outv deliberately NOT __restrict__ — the EMB instantiation runs
// in-place (outv==Av); restrict there was UB.
template<bool ABF16, int MODE>
__global__ __launch_bounds__(256, 2)
void gemm_k(const void* Av, const bf16_t* __restrict__ Wt,
            const float* __restrict__ bias, void* outv, int M,
            const int* __restrict__ z, const float* __restrict__ emb,
            float* __restrict__ out2, const float* __restrict__ bias2)
{
  __shared__ bf16_t As[128 * 40];
  __shared__ bf16_t Bs[320 * 40];
  const int tid = threadIdx.x;
  const int wave = tid >> 6;
  const int lane = tid & 63;
  const int lhalf = lane >> 5;
  const int l31 = lane & 31;
  const int m0 = blockIdx.x * 128;

  f32x16 acc[2][5] = {};

  for (int k0 = 0; k0 < LDP; k0 += 32) {
    #pragma unroll
    for (int i = 0; i < 5; i++) {
      int idx = tid + i * 256;
      int n = idx >> 2, cv = idx & 3;
      *(bf16x8*)&Bs[n * 40 + cv * 8] =
          *(const bf16x8*)(Wt + (size_t)n * LDP + k0 + cv * 8);
    }
    if constexpr (ABF16) {
      const bf16_t* A = (const bf16_t*)Av;
      #pragma unroll
      for (int i = 0; i < 2; i++) {
        int r = (tid >> 2) + i * 64;
        int cv = tid & 3;
        int row = m0 + r;
        bf16x8 v = {};
        if (row < M) v = *(const bf16x8*)(A + (size_t)row * LDP + k0 + cv * 8);
        *(bf16x8*)&As[r * 40 + cv * 8] = v;
      }
    } else {
      const float* A = (const float*)Av;
      #pragma unroll
      for (int i = 0; i < 4; i++) {
        int r = (tid >> 3) + i * 32;
        int cv = tid & 7;
        int row = m0 + r;
        float fx = 0.f, fy = 0.f, fz2 = 0.f, fw = 0.f;
        if (row < M) {
          const float4 f = *(const float4*)(A + (size_t)row * LDP + k0 + cv * 4);
          fx = f.x; fy = f.y; fz2 = f.z; fw = f.w;
        }
        bf16x4 v;
        v.x = (bf16_t)fx; v.y = (bf16_t)fy; v.z = (bf16_t)fz2; v.w = (bf16_t)fw;
        *(bf16x4*)&As[r * 40 + cv * 4] = v;
      }
    }
    __syncthreads();
    #pragma unroll
    for (int ks = 0; ks < 2; ks++) {
      const int kk = ks * 16 + lhalf * 8;
      bf16x8 af0 = *(const bf16x8*)&As[((wave & 1) * 64 + 0  + l31) * 40 + kk];
      bf16x8 af1 = *(const bf16x8*)&As[((wave & 1) * 64 + 32 + l31) * 40 + kk];
      #pragma unroll
      for (int cf = 0; cf < 5; cf++) {
        bf16x8 bv = *(const bf16x8*)&Bs[((wave >> 1) * 160 + cf * 32 + l31) * 40 + kk];
        acc[0][cf] = __builtin_amdgcn_mfma_f32_32x32x16_bf16(af0, bv, acc[0][cf], 0, 0, 0);
        acc[1][cf] = __builtin_amdgcn_mfma_f32_32x32x16_bf16(af1, bv, acc[1][cf], 0, 0, 0);
      }
    }
    __syncthreads();
  }

  const int colb = (wave >> 1) * 160;
  float s1[5], s2[5];
  #pragma unroll
  for (int i = 0; i < 5; i++) { s1[i] = 0.f; s2[i] = 0.f; }

  #pragma unroll
  for (int rf = 0; rf < 2; rf++) {
    const int rowb = m0 + (wave & 1) * 64 + rf * 32 + 4 * lhalf;
    #pragma unroll
    for (int cf = 0; cf < 5; cf++) {
      const int col = colb + cf * 32 + l31;
      float bv;
      if constexpr (MODE == MODE_HEAD) {
        bv = (col < 87) ? bias[col] : (col < 93 ? bias2[col - 87] : 0.f);
      } else {
        bv = (col < DD) ? bias[col] : 0.f;
      }
      f32x16 v = acc[rf][cf];
      #pragma unroll
      for (int r = 0; r < 16; r++) {
        const int row = rowb + (r & 3) + 8 * (r >> 2);
        if (row >= M) continue;
        float val = v[r] + bv;
        if constexpr (MODE == MODE_F32S) {
          ((float*)outv)[(size_t)row * LDP + col] = val;
          s1[cf] += val; s2[cf] += val * val;
        } else if constexpr (MODE == MODE_BF16_RELU) {
          ((bf16_t*)outv)[(size_t)row * LDP + col] = (bf16_t)fmaxf(val, 0.f);
        } else if constexpr (MODE == MODE_BF16) {
          ((bf16_t*)outv)[(size_t)row * LDP + col] = (bf16_t)val;
        } else if constexpr (MODE == MODE_EMB) {
          float add = (col < DD) ? emb[(size_t)z[row] * DD + col] : 0.f;
          ((bf16_t*)outv)[(size_t)row * LDP + col] = (bf16_t)(val + add);
        } else {  // MODE_HEAD: fp32 outputs
          if (col < 87) ((float*)outv)[(size_t)row * 87 + col] = val;
          else if (col < 93) out2[(size_t)row * 6 + (col - 87)] = val;
        }
      }
    }
  }

  if constexpr (MODE == MODE_F32S) {
    // combine the two half-wave partners (same col, different rows), then one
    // atomic per column per block into sums[col] / sums[LDP+col].
    #pragma unroll
    for (int cf = 0; cf < 5; cf++) {
      const int col = colb + cf * 32 + l31;
      float o1 = __shfl_down(s1[cf], 32);
      float o2 = __shfl_down(s2[cf], 32);
      if (lhalf == 0 && col < DD) {
        atomicAdd(&out2[col], s1[cf] + o1);
        atomicAdd(&out2[LDP + col], s2[cf] + o2);
      }
    }
  }
}

__global__ void stage1_node(const float* __restrict__ ch, const float* __restrict__ fc,
                            const float* __restrict__ w1, const float* __restrict__ b1,
                            bf16_t* __restrict__ t, int n) {
  int idx = blockIdx.x * 256 + threadIdx.x;
  if (idx >= n * LDP) return;
  int i = idx / LDP;
  int c = idx - i * LDP;
  float v = 0.f;
  if (c < DD) v = fmaxf(ch[i] * w1[c] + fc[i] * w1[DD + c] + b1[c], 0.f);
  t[idx] = (bf16_t)v;
}

__global__ void stage1_edge(const float* __restrict__ ea,
                            const float* __restrict__ w1, const float* __restrict__ b1,
                            bf16_t* __restrict__ t, int n) {
  int idx = blockIdx.x * 256 + threadIdx.x;
  if (idx >= n * LDP) return;
  int i = idx / LDP;
  int c = idx - i * LDP;
  float v = 0.f;
  if (c < DD) {
    float a0 = ea[(long)i * 3 + 0], a1 = ea[(long)i * 3 + 1], a2 = ea[(long)i * 3 + 2];
    v = fmaxf(a0 * w1[c] + a1 * w1[DD + c] + a2 * w1[2 * DD + c] + b1[c], 0.f);
  }
  t[idx] = (bf16_t)v;
}

// hh = (float)h (GINE eps=0 self term); atomics accumulate on top. Layer 0 only;
// layers 1..4 get hh written by bn_apply.
__global__ void init_hh(const bf16_t* __restrict__ h, float* __restrict__ hh, int total) {
  int idx = blockIdx.x * 256 + threadIdx.x;
  if (idx >= total) return;
  hh[idx] = (float)h[idx];
}

// hh += scatter_add over dst of relu(h[src] + e)
__global__ void scatter_k(const bf16_t* __restrict__ h, const bf16_t* __restrict__ e,
                          const int* __restrict__ src, const int* __restrict__ dst,
                          float* __restrict__ hh, int E) {
  int idx = blockIdx.x * 256 + threadIdx.x;
  if (idx >= E * 75) return;
  int ed = idx / 75;
  int q = idx - ed * 75;
  int s = src[ed], d = dst[ed];
  const bf16x4 hv = *(const bf16x4*)(h + (size_t)s * LDP + q * 4);
  const bf16x4 ev = *(const bf16x4*)(e + (size_t)ed * LDP + q * 4);
  float* o = hh + (size_t)d * LDP + q * 4;
  atomicAdd(o + 0, fmaxf((float)hv.x + (float)ev.x, 0.f));
  atomicAdd(o + 1, fmaxf((float)hv.y + (float)ev.y, 0.f));
  atomicAdd(o + 2, fmaxf((float)hv.z + (float)ev.z, 0.f));
  atomicAdd(o + 3, fmaxf((float)hv.w + (float)ev.w, 0.f));
}

__global__ void zero_sums(float* __restrict__ sums) { sums[threadIdx.x] = 0.f; }

__global__ void bn_final(const float* __restrict__ sums, const float* __restrict__ gamma,
                         const float* __restrict__ beta, float* __restrict__ ab, int n) {
  int c = threadIdx.x;
  if (c >= DD) return;
  float inv_n = 1.f / (float)n;
  float mean = sums[c] * inv_n;
  float var = sums[LDP + c] * inv_n - mean * mean;  // biased var (torch/jnp)
  float a = gamma[c] * rsqrtf(fmaxf(var, 0.f) + 1e-5f);
  ab[c] = a;
  ab[LDP + c] = beta[c] - mean * a;
}

// h(bf16) = relu(BN(u));  u(fp32, in-place) = same value -> next layer's
// scatter base (replaces init_hh for layers 1..4).
__global__ void bn_apply(float* u, const float* __restrict__ ab,
                         bf16_t* __restrict__ h, int total) {
  int idx = blockIdx.x * 256 + threadIdx.x;
  if (idx >= total) return;
  int c = idx % LDP;
  float v = 0.f;
  if (c < DD) v = fmaxf(u[idx] * ab[c] + ab[LDP + c], 0.f);
  h[idx] = (bf16_t)v;  // pad columns stay zero
  u[idx] = v;
}

extern "C" void kernel_launch(void* const* d_in, const int* in_sizes, int n_in,
                              void* d_out, int out_size, void* d_ws, size_t ws_size,
                              hipStream_t stream) {
  const int*   z        = (const int*)d_in[0];
  const float* chir     = (const float*)d_in[1];
  const float* fchg     = (const float*)d_in[2];
  const int*   eidx     = (const int*)d_in[3];
  const float* eattr    = (const float*)d_in[4];
  const float* atom_emb = (const float*)d_in[5];
  const float* nap_w1   = (const float*)d_in[6];
  const float* nap_b1   = (const float*)d_in[7];
  const float* nap_w2   = (const float*)d_in[8];
  const float* nap_b2   = (const float*)d_in[9];
  const float* ee_w1    = (const float*)d_in[10];
  const float* ee_b1    = (const float*)d_in[11];
  const float* ee_w2    = (const float*)d_in[12];
  const float* ee_b2    = (const float*)d_in[13];
  const float* gnn_w1   = (const float*)d_in[14];
  const float* gnn_b1   = (const float*)d_in[15];
  const float* gnn_w2   = (const float*)d_in[16];
  const float* gnn_b2   = (const float*)d_in[17];
  const float* bn_gamma = (const float*)d_in[18];
  const float* bn_beta  = (const float*)d_in[19];
  const float* ah_w     = (const float*)d_in[20];
  const float* ah_b     = (const float*)d_in[21];
  const float* ch_w     = (const float*)d_in[22];
  const float* ch_b     = (const float*)d_in[23];

  const int N = in_sizes[0];
  const int E = in_sizes[3] / 2;
  const int* src = eidx;
  const int* dst = eidx + E;

  char* ws = (char*)d_ws;
  size_t off = 0;
  auto take = [&](size_t bytes) -> void* {
    void* p = ws + off;
    off = (off + bytes + 255) & ~(size_t)255;
    return p;
  };
  bf16_t* wt12 = (bf16_t*)take((size_t)12 * WSLOT * 2);
  bf16_t* wtH  = (bf16_t*)take((size_t)WSLOT * 2);
  float*  sums = (float*)take((size_t)2 * LDP * 4);
  float*  ab   = (float*)take((size_t)2 * LDP * 4);
  bf16_t* h    = (bf16_t*)take((size_t)N * LDP * 2);   // bf16 activations / MLP temp
  float*  hh   = (float*)take((size_t)N * LDP * 4);    // fp32 aggregate / pre-BN
  const size_t base_end = off;
  if (ws_size < base_end) return;  // can't run safely -> diagnostic zero output

  const size_t e_bytes = (size_t)E * LDP * 2;
  const bool persist_e = (ws_size >= base_end + e_bytes + 256) &&
                         (e_bytes <= (size_t)N * LDP * 4);  // estage aliases hh
  bf16_t* e_full = nullptr;
  bf16_t* echunk = nullptr;
  int EC = 0;
  if (persist_e) {
    e_full = (bf16_t*)take(e_bytes);
  } else {
    size_t slack = (ws_size > base_end + 256) ? (ws_size - base_end - 256) : 0;
    size_t ec_ws  = slack / (LDP * 2);
    size_t ec_out = ((size_t)out_size * 4) / (LDP * 2);
    size_t ec = ec_ws < ec_out ? ec_ws : ec_out;
    if (ec > (size_t)E) ec = E;
    ec &= ~(size_t)127;
    if (ec < 128) return;
    EC = (int)ec;
    echunk = (bf16_t*)take((size_t)EC * LDP * 2);
  }
  (void)n_in;

  Src12 s;
  s.p[0] = nap_w2; s.p[1] = ee_w2;
  for (int l = 0; l < 5; l++) {
    s.p[2 + l] = gnn_w1 + (size_t)l * DD * DD;
    s.p[7 + l] = gnn_w2 + (size_t)l * DD * DD;
  }
  prep_wt_all<<<dim3((WSLOT + 255) / 256, 12), 256, 0, stream>>>(s, wt12);
  prep_wt_head<<<(WSLOT + 255) / 256, 256, 0, stream>>>(ah_w, ch_w, wtH);

  const int gN = (N + 127) / 128;

  if (persist_e) {
    bf16_t* estage = (bf16_t*)hh;  // hh dead until first init_hh
    stage1_edge<<<((long)E * LDP + 255) / 256, 256, 0, stream>>>(eattr, ee_w1, ee_b1, estage, E);
    gemm_k<true, MODE_BF16><<<(E + 127) / 128, 256, 0, stream>>>(
        estage, wt12 + (size_t)1 * WSLOT, ee_b2, e_full, E, nullptr, nullptr, nullptr, nullptr);
  }

  // node init: h = atom_emb[z] + relu(na@nap_w1+b1)@nap_w2+b2  (bf16, in-place)
  stage1_node<<<((long)N * LDP + 255) / 256, 256, 0, stream>>>(chir, fchg, nap_w1, nap_b1, h, N);
  gemm_k<true, MODE_EMB><<<gN, 256, 0, stream>>>(
      h, wt12 + (size_t)0 * WSLOT, nap_b2, h, N, z, atom_emb, nullptr, nullptr);

  for (int l = 0; l < 5; l++) {
    if (l == 0)  // layers 1..4: bn_apply already wrote hh = h
      init_hh<<<((long)N * LDP + 255) / 256, 256, 0, stream>>>(h, hh, N * LDP);
    if (persist_e) {
      scatter_k<<<((long)E * 75 + 255) / 256, 256, 0, stream>>>(h, e_full, src, dst, hh, E);
    } else {
      bf16_t* estage = (bf16_t*)d_out;  // legal scratch until final head GEMM
      for (int c0 = 0; c0 < E; c0 += EC) {
        int curn = (E - c0 < EC) ? (E - c0) : EC;
        stage1_edge<<<((long)curn * LDP + 255) / 256, 256, 0, stream>>>(
            eattr + (size_t)c0 * 3, ee_w1, ee_b1, estage, curn);
        gemm_k<true, MODE_BF16><<<(curn + 127) / 128, 256, 0, stream>>>(
            estage, wt12 + (size_t)1 * WSLOT, ee_b2, echunk, curn,
            nullptr, nullptr, nullptr, nullptr);
        scatter_k<<<((long)curn * 75 + 255) / 256, 256, 0, stream>>>(
            h, echunk, src + c0, dst + c0, hh, curn);
      }
    }
    // t(=h buffer) = relu(hh@W1+b1)
    gemm_k<false, MODE_BF16_RELU><<<gN, 256, 0, stream>>>(
        hh, wt12 + (size_t)(2 + l) * WSLOT, gnn_b1 + (size_t)l * DD, h, N,
        nullptr, nullptr, nullptr, nullptr);
    // hh = t@W2+b2 with fused BN column stats
    zero_sums<<<1, 2 * LDP, 0, stream>>>(sums);
    gemm_k<true, MODE_F32S><<<gN, 256, 0, stream>>>(
        h, wt12 + (size_t)(7 + l) * WSLOT, gnn_b2 + (size_t)l * DD, hh, N,
        nullptr, nullptr, sums, nullptr);
    bn_final<<<1, LDP, 0, stream>>>(sums, bn_gamma + (size_t)l * DD, bn_beta + (size_t)l * DD, ab, N);
    // h = relu(BN(hh)) and hh = same (fp32) for next layer's scatter base
    bn_apply<<<((long)N * LDP + 255) / 256, 256, 0, stream>>>(hh, ab, h, N * LDP);
  }

  // heads: logits [N,87] ++ dists [N,6] into fp32 d_out
  gemm_k<true, MODE_HEAD><<<gN, 256, 0, stream>>>(
      h, wtH, ah_b, d_out, N, nullptr, nullptr, (float*)d_out + (size_t)N * 87, ch_b);
}